// Round 5
// baseline (871.365 us; speedup 1.0000x reference)
//
#include <hip/hip_runtime.h>
#include <math.h>

// Problem dims (fixed by reference)
#define Bsz 64
#define Ssz 512
#define Hsz 400
#define Dsz 400
#define Vsz 32000
#define Lsz 16
#define H3  1200   // 3*H

// Workspace layout (float offsets)
#define WT_HH_OFF 0                 // 400*1200 transposed W_hh [k][j]  (fallback only)
#define WT_IH_OFF 480000            // 400*1200 transposed W_ih [k][j]  (fallback only)
#define HQA_OFF   960000            // 25600  h ping  (float4 tiles [k4][b][4])
#define HQB_OFF   985600            // 25600  h pong
#define GI_OFF    1011200           // 16*1200*64   gi[t][j][b]
#define HALL_OFF  2240000           // 64*16*400    h_all[b][t][d]
#define SCALL_OFF 2649600           // 16*64*512    scores[t][b][s]
#define CTR_OFF   3173888           // barrier counter (uint) + pad
// total 3,173,952 floats = 12.7 MB

#define NCHAIN 80                   // d-sliced chain blocks (5 d each)

// ---------------------------------------------------------------------------
// k_init: one grid-stride kernel doing (a) zero 131 MB output, (b) WT
// transposes for the tf==0 fallback, (c) h0 into hqA, (d) zero barrier ctr.
// ---------------------------------------------------------------------------
__global__ __launch_bounds__(256) void k_init(const float* __restrict__ W_hh,
                                              const float* __restrict__ W_ih,
                                              const float* __restrict__ enc_hidden,
                                              float4* __restrict__ out4, int n4,
                                              float* __restrict__ ws) {
    const int R1 = n4 + 480000;
    const int R2 = R1 + 480000;
    const int R3 = R2 + 25600;
    const int R4 = R3 + 64;
    int stride = gridDim.x * 256;
    for (int i = blockIdx.x * 256 + threadIdx.x; i < R4; i += stride) {
        if (i < n4) {
            out4[i] = make_float4(0.f, 0.f, 0.f, 0.f);
        } else if (i < R1) {
            int r = i - n4;
            int k = r / 1200, j = r % 1200;
            ws[WT_HH_OFF + r] = W_hh[(size_t)j * Hsz + k];
        } else if (i < R2) {
            int r = i - R1;
            int k = r / 1200, j = r % 1200;
            ws[WT_IH_OFF + r] = W_ih[(size_t)j * Dsz + k];
        } else if (i < R3) {
            int r = i - R2;
            int k = r >> 6, b = r & 63;
            ws[HQA_OFF + (k >> 2) * 256 + b * 4 + (k & 3)] = enc_hidden[b * Hsz + k];
        } else {
            ((unsigned*)(ws + CTR_OFF))[i - R3] = 0u;
        }
    }
}

// ---------------------------------------------------------------------------
// k_gi (tf==1 only): gi[t][j][b] = (x_t[b] @ W_ih^T)[j], tiled GEMM.
// 256 blocks = 16 t x 16 jc (75 j each). x_t staged in LDS [k4][b] float4;
// W_ih rows read wave-uniform (scalar path); 4-j register tile.
// ---------------------------------------------------------------------------
__global__ __launch_bounds__(256) void k_gi(const int* __restrict__ tgt,
                                            const int* __restrict__ slot_p,
                                            const int* __restrict__ tf_p,
                                            const float* __restrict__ embedding,
                                            const float* __restrict__ slot_emb,
                                            const float* __restrict__ W_ih,
                                            float* __restrict__ gi) {
    if (tf_p[0] == 0) return;
    __shared__ float4 xs[100 * 64];   // 102.4 KB, [k4][b]

    int t  = blockIdx.x >> 4;
    int jc = blockIdx.x & 15;
    int tid = threadIdx.x;
    int lane = tid & 63, wv = tid >> 6;

    // stage x_t: thread (b, quarter q) loads 25 float4
    {
        int bb = tid & 63, q = tid >> 6;
        const float* src = (t == 0)
            ? (slot_emb + (size_t)slot_p[0] * Dsz)
            : (embedding + (size_t)tgt[bb * Lsz + (t - 1)] * Dsz);
        const float4* src4 = (const float4*)src;
        for (int k4 = q * 25; k4 < q * 25 + 25; ++k4) xs[k4 * 64 + bb] = src4[k4];
    }
    __syncthreads();

    // 75 j per block = 19 groups of 4 (last has 3). Wave wv takes g = wv, wv+4, ...
    for (int g = wv; g < 19; g += 4) {
        int j0l = g * 4;
        int nj = (j0l + 4 <= 75) ? 4 : (75 - j0l);
        int j0 = jc * 75 + j0l;
        const float4* w0 = (const float4*)(W_ih + (size_t)(j0 + 0) * Dsz);
        const float4* w1 = (const float4*)(W_ih + (size_t)(j0 + ((nj > 1) ? 1 : 0)) * Dsz);
        const float4* w2 = (const float4*)(W_ih + (size_t)(j0 + ((nj > 2) ? 2 : 0)) * Dsz);
        const float4* w3 = (const float4*)(W_ih + (size_t)(j0 + ((nj > 3) ? 3 : 0)) * Dsz);
        float a0 = 0.f, a1 = 0.f, a2 = 0.f, a3 = 0.f;
        for (int k4 = 0; k4 < 100; ++k4) {
            float4 xv = xs[k4 * 64 + lane];
            float4 r0 = w0[k4], r1 = w1[k4], r2 = w2[k4], r3 = w3[k4];
            a0 = fmaf(r0.x, xv.x, a0); a0 = fmaf(r0.y, xv.y, a0);
            a0 = fmaf(r0.z, xv.z, a0); a0 = fmaf(r0.w, xv.w, a0);
            a1 = fmaf(r1.x, xv.x, a1); a1 = fmaf(r1.y, xv.y, a1);
            a1 = fmaf(r1.z, xv.z, a1); a1 = fmaf(r1.w, xv.w, a1);
            a2 = fmaf(r2.x, xv.x, a2); a2 = fmaf(r2.y, xv.y, a2);
            a2 = fmaf(r2.z, xv.z, a2); a2 = fmaf(r2.w, xv.w, a2);
            a3 = fmaf(r3.x, xv.x, a3); a3 = fmaf(r3.y, xv.y, a3);
            a3 = fmaf(r3.z, xv.z, a3); a3 = fmaf(r3.w, xv.w, a3);
        }
        float* go = gi + ((size_t)t * H3 + j0) * 64 + lane;
        go[0] = a0;
        if (nj > 1) go[64] = a1;
        if (nj > 2) go[128] = a2;
        if (nj > 3) go[192] = a3;
    }
}

// ---------------------------------------------------------------------------
// k_chain: merged kernel.
//  tf==1: 80 d-sliced blocks x 960 threads. Block owns 5 d (15 W_hh rows,
//   24 KB LDS, loaded once). Per step: stage h (102 KB) -> GEMV from LDS ->
//   finalize own d-slice -> device-atomic barrier (15 total).
//  tf==0: blocks 0..63 run the independent per-batch full decode (fallback).
// ---------------------------------------------------------------------------
struct SmemChain {
    float4 W4[15 * 100];    // 24.0 KB  W_hh slice rows
    float4 h4[100 * 64];    // 102.4 KB h staged [k4][b]
    float  part[2880];      // 11.5 KB  [ks][gate][dd][b]
};
struct SmemFallback {
    float part_i[3 * H3];
    float part_h[3 * H3];
    float hx[Hsz];
    float xv[Dsz];
    float sL[Ssz];
    float redv[15];
    int   redi[15];
    float bc_max, bc_sum;
    int   bc_idx;
};
union SmemU { SmemChain c; SmemFallback f; };

__device__ __forceinline__ float sigmoidf_(float x) { return 1.f / (1.f + expf(-x)); }

__global__ __launch_bounds__(960) void k_chain(const float* __restrict__ ws_ro,
                                               const float* __restrict__ gi,
                                               const float* __restrict__ W_hh,
                                               const float* __restrict__ enc_hidden,
                                               const float* __restrict__ enc_out,
                                               const int* __restrict__ lens,
                                               const int* __restrict__ uttrs,
                                               const int* __restrict__ slot_p,
                                               const int* __restrict__ tf_p,
                                               const float* __restrict__ embedding,
                                               const float* __restrict__ slot_emb,
                                               const float* __restrict__ b_ih,
                                               const float* __restrict__ b_hh,
                                               float* __restrict__ ws_rw,
                                               float* __restrict__ h_all,
                                               float* __restrict__ out_probs,
                                               float* __restrict__ preds_out) {
    __shared__ SmemU sm;
    const int tid = threadIdx.x;
    const int tf  = tf_p[0];

    if (tf != 0) {
        // ================= distributed h-chain =================
        const int b  = tid & 63;
        const int wv = tid >> 6;            // 0..14
        const int dd_w = wv % 5;
        const int ks   = wv / 5;            // 0..2
        const int D0 = blockIdx.x * 5;
        unsigned* ctr = (unsigned*)(ws_rw + CTR_OFF);

        // preload W_hh slice: 15 rows x 100 float4
        for (int i = tid; i < 1500; i += 960) {
            int row = i / 100, k4 = i % 100;
            int g = row / 5, dd = row % 5;
            sm.c.W4[row * 100 + k4] =
                ((const float4*)(W_hh + (size_t)(g * Hsz + D0 + dd) * Hsz))[k4];
        }
        __syncthreads();

        const int k4beg = (ks == 0) ? 0 : (ks == 1) ? 34 : 68;
        const int k4end = (ks == 2) ? 100 : k4beg + 34;
        const float4* Wr = sm.c.W4 + (0 * 5 + dd_w) * 100;
        const float4* Wz = sm.c.W4 + (1 * 5 + dd_w) * 100;
        const float4* Wn = sm.c.W4 + (2 * 5 + dd_w) * 100;

        for (int t = 0; t < Lsz; ++t) {
            const float4* hq_cur = (const float4*)(ws_ro + ((t & 1) ? HQB_OFF : HQA_OFF));
            float*        hq_nxt = ws_rw + ((t & 1) ? HQA_OFF : HQB_OFF);

            for (int i = tid; i < 6400; i += 960) sm.c.h4[i] = hq_cur[i];
            __syncthreads();

            float ar = 0.f, az = 0.f, an = 0.f;
            for (int k4 = k4beg; k4 < k4end; ++k4) {
                float4 hv = sm.c.h4[k4 * 64 + b];
                float4 wr = Wr[k4], wz = Wz[k4], wn = Wn[k4];
                ar = fmaf(wr.x, hv.x, ar); ar = fmaf(wr.y, hv.y, ar);
                ar = fmaf(wr.z, hv.z, ar); ar = fmaf(wr.w, hv.w, ar);
                az = fmaf(wz.x, hv.x, az); az = fmaf(wz.y, hv.y, az);
                az = fmaf(wz.z, hv.z, az); az = fmaf(wz.w, hv.w, az);
                an = fmaf(wn.x, hv.x, an); an = fmaf(wn.y, hv.y, an);
                an = fmaf(wn.z, hv.z, an); an = fmaf(wn.w, hv.w, an);
            }
            sm.c.part[((ks * 3 + 0) * 5 + dd_w) * 64 + b] = ar;
            sm.c.part[((ks * 3 + 1) * 5 + dd_w) * 64 + b] = az;
            sm.c.part[((ks * 3 + 2) * 5 + dd_w) * 64 + b] = an;
            __syncthreads();

            if (tid < 320) {
                int b2 = tid & 63, dd = tid >> 6;
                int d = D0 + dd;
                float ghr = sm.c.part[((0 * 3 + 0) * 5 + dd) * 64 + b2]
                          + sm.c.part[((1 * 3 + 0) * 5 + dd) * 64 + b2]
                          + sm.c.part[((2 * 3 + 0) * 5 + dd) * 64 + b2] + b_hh[d];
                float ghz = sm.c.part[((0 * 3 + 1) * 5 + dd) * 64 + b2]
                          + sm.c.part[((1 * 3 + 1) * 5 + dd) * 64 + b2]
                          + sm.c.part[((2 * 3 + 1) * 5 + dd) * 64 + b2] + b_hh[d + Hsz];
                float ghn = sm.c.part[((0 * 3 + 2) * 5 + dd) * 64 + b2]
                          + sm.c.part[((1 * 3 + 2) * 5 + dd) * 64 + b2]
                          + sm.c.part[((2 * 3 + 2) * 5 + dd) * 64 + b2] + b_hh[d + 2 * Hsz];
                float gir = gi[((size_t)t * H3 + d) * 64 + b2]            + b_ih[d];
                float giz = gi[((size_t)t * H3 + d + Hsz) * 64 + b2]      + b_ih[d + Hsz];
                float gin = gi[((size_t)t * H3 + d + 2 * Hsz) * 64 + b2]  + b_ih[d + 2 * Hsz];
                float r = sigmoidf_(gir + ghr);
                float z = sigmoidf_(giz + ghz);
                float n = tanhf(gin + r * ghn);
                float hp = ((const float*)sm.c.h4)[((d >> 2) * 64 + b2) * 4 + (d & 3)];
                float hn = (1.f - z) * n + z * hp;
                hq_nxt[(d >> 2) * 256 + b2 * 4 + (d & 3)] = hn;
                h_all[(size_t)b2 * (Lsz * Hsz) + t * Hsz + d] = hn;
            }

            if (t < Lsz - 1) {
                __threadfence();
                __syncthreads();
                if (tid == 0) {
                    atomicAdd(ctr, 1u);
                    unsigned target = (unsigned)NCHAIN * (t + 1);
                    while (__hip_atomic_load(ctr, __ATOMIC_ACQUIRE,
                                             __HIP_MEMORY_SCOPE_AGENT) < target) {
                        __builtin_amdgcn_s_sleep(2);
                    }
                }
                __syncthreads();
            }
        }
        return;
    }

    // ================= tf==0 fallback: per-batch independent decode =========
    if (blockIdx.x >= Bsz) return;
    const int b    = blockIdx.x;
    const int lane = tid & 63;
    const int w    = tid >> 6;          // 0..14
    const int jc   = tid % 300;
    const int ksf  = tid / 300;
    const int kbeg = ksf * 134;
    const int kend = (ksf == 2) ? Hsz : kbeg + 134;
    const int len  = lens[b];

    const float4* WTH4 = (const float4*)(ws_ro + WT_HH_OFF);
    const float4* WTI4 = (const float4*)(ws_ro + WT_IH_OFF);

    if (tid < Hsz) {
        sm.f.hx[tid] = enc_hidden[b * Hsz + tid];
        sm.f.xv[tid] = slot_emb[(size_t)slot_p[0] * Dsz + tid];
    }
    __syncthreads();

    for (int t = 0; t < Lsz; ++t) {
        if (tid < 900) {
            float4 ai = make_float4(0.f, 0.f, 0.f, 0.f);
            float4 ah = make_float4(0.f, 0.f, 0.f, 0.f);
            for (int k = kbeg; k < kend; ++k) {
                float4 wi = WTI4[(size_t)k * 300 + jc];
                float4 wh = WTH4[(size_t)k * 300 + jc];
                float x = sm.f.xv[k], h = sm.f.hx[k];
                ai.x = fmaf(wi.x, x, ai.x); ai.y = fmaf(wi.y, x, ai.y);
                ai.z = fmaf(wi.z, x, ai.z); ai.w = fmaf(wi.w, x, ai.w);
                ah.x = fmaf(wh.x, h, ah.x); ah.y = fmaf(wh.y, h, ah.y);
                ah.z = fmaf(wh.z, h, ah.z); ah.w = fmaf(wh.w, h, ah.w);
            }
            ((float4*)sm.f.part_i)[ksf * 300 + jc] = ai;
            ((float4*)sm.f.part_h)[ksf * 300 + jc] = ah;
        }
        __syncthreads();

        if (tid < Hsz) {
            int d = tid;
            float i_r = sm.f.part_i[d]           + sm.f.part_i[H3 + d]           + sm.f.part_i[2 * H3 + d]           + b_ih[d];
            float i_z = sm.f.part_i[d + Hsz]     + sm.f.part_i[H3 + d + Hsz]     + sm.f.part_i[2 * H3 + d + Hsz]     + b_ih[d + Hsz];
            float i_n = sm.f.part_i[d + 2 * Hsz] + sm.f.part_i[H3 + d + 2 * Hsz] + sm.f.part_i[2 * H3 + d + 2 * Hsz] + b_ih[d + 2 * Hsz];
            float h_r = sm.f.part_h[d]           + sm.f.part_h[H3 + d]           + sm.f.part_h[2 * H3 + d]           + b_hh[d];
            float h_z = sm.f.part_h[d + Hsz]     + sm.f.part_h[H3 + d + Hsz]     + sm.f.part_h[2 * H3 + d + Hsz]     + b_hh[d + Hsz];
            float h_n = sm.f.part_h[d + 2 * Hsz] + sm.f.part_h[H3 + d + 2 * Hsz] + sm.f.part_h[2 * H3 + d + 2 * Hsz] + b_hh[d + 2 * Hsz];
            float r = sigmoidf_(i_r + h_r);
            float z = sigmoidf_(i_z + h_z);
            float n = tanhf(i_n + r * h_n);
            sm.f.hx[d] = (1.f - z) * n + z * sm.f.hx[d];
        }
        __syncthreads();

        const float4* hx4 = (const float4*)sm.f.hx;
        for (int s = w; s < len; s += 15) {
            const float4* e4 = (const float4*)(enc_out + ((size_t)b * Ssz + s) * Hsz);
            float4 ev = e4[lane];
            float4 hv = hx4[lane];
            float acc = ev.x * hv.x + ev.y * hv.y + ev.z * hv.z + ev.w * hv.w;
            if (lane < 36) {
                float4 ev2 = e4[64 + lane];
                float4 hv2 = hx4[64 + lane];
                acc += ev2.x * hv2.x + ev2.y * hv2.y + ev2.z * hv2.z + ev2.w * hv2.w;
            }
            #pragma unroll
            for (int off = 32; off >= 1; off >>= 1) acc += __shfl_xor(acc, off, 64);
            if (lane == 0) sm.f.sL[s] = acc;
        }
        __syncthreads();

        float bv = -INFINITY; int bi = 0x7fffffff;
        for (int s = tid; s < len; s += 960) {
            float v = sm.f.sL[s];
            if (v > bv || (v == bv && s < bi)) { bv = v; bi = s; }
        }
        #pragma unroll
        for (int off = 32; off >= 1; off >>= 1) {
            float ov = __shfl_xor(bv, off, 64);
            int   oi = __shfl_xor(bi, off, 64);
            if (ov > bv || (ov == bv && oi < bi)) { bv = ov; bi = oi; }
        }
        if (lane == 0) { sm.f.redv[w] = bv; sm.f.redi[w] = bi; }
        __syncthreads();
        if (tid == 0) {
            float mv = sm.f.redv[0]; int mi = sm.f.redi[0];
            for (int i = 1; i < 15; ++i)
                if (sm.f.redv[i] > mv || (sm.f.redv[i] == mv && sm.f.redi[i] < mi)) {
                    mv = sm.f.redv[i]; mi = sm.f.redi[i];
                }
            sm.f.bc_max = mv; sm.f.bc_idx = mi;
        }
        __syncthreads();
        float maxv = sm.f.bc_max;
        int   amax = sm.f.bc_idx;

        float ls = 0.f;
        for (int s = tid; s < len; s += 960) {
            float e = expf(sm.f.sL[s] - maxv);
            sm.f.sL[s] = e;
            ls += e;
        }
        #pragma unroll
        for (int off = 32; off >= 1; off >>= 1) ls += __shfl_xor(ls, off, 64);
        if (lane == 0) sm.f.redv[w] = ls;
        __syncthreads();
        if (tid == 0) {
            float sms = 0.f;
            for (int i = 0; i < 15; ++i) sms += sm.f.redv[i];
            sm.f.bc_sum = sms;
        }
        __syncthreads();
        float sum = sm.f.bc_sum;

        float* orow = out_probs + (size_t)b * (Lsz * Vsz) + (size_t)t * Vsz;
        for (int s = tid; s < len; s += 960) {
            atomicAdd(&orow[uttrs[b * Ssz + s]], sm.f.sL[s] / sum);
        }

        int predtok = uttrs[b * Ssz + amax];
        if (tid == 0) preds_out[(size_t)t * Bsz + b] = (float)predtok;
        __syncthreads();
        if (tid < Dsz) sm.f.xv[tid] = embedding[(size_t)predtok * Dsz + tid];
        __syncthreads();
    }
}

// ---------------------------------------------------------------------------
// Batched scores (tf==1): scores[t][b][s] = h_t[b].enc_out[b][s], s < len[b].
// ---------------------------------------------------------------------------
__global__ __launch_bounds__(256) void k_scores(const float* __restrict__ h_all,
                                                const float* __restrict__ enc_out,
                                                const int* __restrict__ lens,
                                                const int* __restrict__ tf_p,
                                                float* __restrict__ scores_all) {
    if (tf_p[0] == 0) return;
    __shared__ float4 hS[Lsz * 100];   // 25.6 KB

    int b  = blockIdx.x >> 3;
    int sc = blockIdx.x & 7;
    int tid = threadIdx.x;
    int lane = tid & 63;
    int w = tid >> 6;

    const float4* h4g = (const float4*)(h_all + (size_t)b * (Lsz * Hsz));
    for (int i = tid; i < Lsz * 100; i += 256) hS[i] = h4g[i];
    __syncthreads();

    int len = lens[b];
    int l2 = 64 + ((lane < 36) ? lane : 0);
    float mult2 = (lane < 36) ? 1.f : 0.f;

    for (int i = 0; i < 16; ++i) {
        int s = sc * 64 + i * 4 + w;
        if (s >= len) continue;
        const float4* e4 = (const float4*)(enc_out + ((size_t)b * Ssz + s) * Hsz);
        float4 ev  = e4[lane];
        float4 ev2 = e4[l2];
        ev2.x *= mult2; ev2.y *= mult2; ev2.z *= mult2; ev2.w *= mult2;

        float acc[Lsz];
        #pragma unroll
        for (int t = 0; t < Lsz; ++t) {
            float4 hv  = hS[t * 100 + lane];
            float4 hv2 = hS[t * 100 + l2];
            float a = ev.x * hv.x + ev.y * hv.y + ev.z * hv.z + ev.w * hv.w;
            a += ev2.x * hv2.x + ev2.y * hv2.y + ev2.z * hv2.z + ev2.w * hv2.w;
            acc[t] = a;
        }
        #pragma unroll
        for (int off = 32; off >= 1; off >>= 1) {
            #pragma unroll
            for (int t = 0; t < Lsz; ++t) acc[t] += __shfl_xor(acc[t], off, 64);
        }
        if (lane == 0) {
            #pragma unroll
            for (int t = 0; t < Lsz; ++t)
                scores_all[(size_t)t * (Bsz * Ssz) + b * Ssz + s] = acc[t];
        }
    }
}

// ---------------------------------------------------------------------------
// Batched softmax + scatter + argmax (tf==1): 1024 blocks, one per (t,b).
// ---------------------------------------------------------------------------
__global__ __launch_bounds__(256) void k_softmax_all(const float* __restrict__ scores_all,
                                                     const int* __restrict__ lens,
                                                     const int* __restrict__ uttrs,
                                                     const int* __restrict__ tf_p,
                                                     float* __restrict__ out_probs,
                                                     float* __restrict__ preds_out) {
    if (tf_p[0] == 0) return;
    __shared__ float sL[Ssz];
    __shared__ float redv[4];
    __shared__ int   redi[4];
    __shared__ float bc_max, bc_sum;
    __shared__ int   bc_idx;

    int t = blockIdx.x >> 6;
    int b = blockIdx.x & 63;
    int tid = threadIdx.x;
    int lane = tid & 63, w = tid >> 6;
    int len = lens[b];
    const float* srow = scores_all + (size_t)t * (Bsz * Ssz) + b * Ssz;

    for (int s = tid; s < len; s += 256) sL[s] = srow[s];
    __syncthreads();

    float bv = -INFINITY; int bi = 0x7fffffff;
    for (int s = tid; s < len; s += 256) {
        float v = sL[s];
        if (v > bv || (v == bv && s < bi)) { bv = v; bi = s; }
    }
    #pragma unroll
    for (int off = 32; off >= 1; off >>= 1) {
        float ov = __shfl_xor(bv, off, 64);
        int   oi = __shfl_xor(bi, off, 64);
        if (ov > bv || (ov == bv && oi < bi)) { bv = ov; bi = oi; }
    }
    if (lane == 0) { redv[w] = bv; redi[w] = bi; }
    __syncthreads();
    if (tid == 0) {
        float mv = redv[0]; int mi = redi[0];
        for (int i = 1; i < 4; ++i)
            if (redv[i] > mv || (redv[i] == mv && redi[i] < mi)) { mv = redv[i]; mi = redi[i]; }
        bc_max = mv; bc_idx = mi;
    }
    __syncthreads();
    float maxv = bc_max;
    int   amax = bc_idx;

    float ls = 0.f;
    for (int s = tid; s < len; s += 256) {
        float e = expf(sL[s] - maxv);
        sL[s] = e;
        ls += e;
    }
    #pragma unroll
    for (int off = 32; off >= 1; off >>= 1) ls += __shfl_xor(ls, off, 64);
    if (lane == 0) redv[w] = ls;
    __syncthreads();
    if (tid == 0) bc_sum = redv[0] + redv[1] + redv[2] + redv[3];
    __syncthreads();
    float sum = bc_sum;

    float* orow = out_probs + (size_t)b * (Lsz * Vsz) + (size_t)t * Vsz;
    for (int s = tid; s < len; s += 256) {
        atomicAdd(&orow[uttrs[b * Ssz + s]], sL[s] / sum);
    }

    if (tid == 0) preds_out[(size_t)t * Bsz + b] = (float)uttrs[b * Ssz + amax];
}

// ---------------------------------------------------------------------------
extern "C" void kernel_launch(void* const* d_in, const int* in_sizes, int n_in,
                              void* d_out, int out_size, void* d_ws, size_t ws_size,
                              hipStream_t stream) {
    const float* enc_hidden = (const float*)d_in[0];
    const float* enc_out    = (const float*)d_in[1];
    const int*   enc_lens   = (const int*)d_in[2];
    const int*   uttrs      = (const int*)d_in[3];
    const int*   tgt        = (const int*)d_in[4];
    const int*   slot_p     = (const int*)d_in[5];
    const int*   tf_p       = (const int*)d_in[6];
    const float* embedding  = (const float*)d_in[7];
    const float* slot_emb   = (const float*)d_in[8];
    const float* W_ih       = (const float*)d_in[9];
    const float* W_hh       = (const float*)d_in[10];
    const float* b_ih       = (const float*)d_in[11];
    const float* b_hh       = (const float*)d_in[12];

    float* out = (float*)d_out;
    float* ws  = (float*)d_ws;

    float* gi_all     = ws + GI_OFF;
    float* h_all      = ws + HALL_OFF;
    float* scores_all = ws + SCALL_OFF;
    float* preds_out  = out + (size_t)Bsz * Lsz * Vsz;

    int n4 = out_size >> 2;   // out_size = B*L*V + L*B, divisible by 4

    // 1) init: zero output + WT transposes + h0 + barrier ctr
    k_init<<<2048, 256, 0, stream>>>(W_hh, W_ih, enc_hidden, (float4*)d_out, n4, ws);

    // 2) gi GEMM for all 16 steps (tf==1 only)
    k_gi<<<256, 256, 0, stream>>>(tgt, slot_p, tf_p, embedding, slot_emb,
                                  W_ih, gi_all);

    // 3) chain (tf==1: d-sliced distributed; tf==0: per-batch fallback)
    k_chain<<<NCHAIN, 960, 0, stream>>>(ws, gi_all, W_hh, enc_hidden, enc_out,
                                        enc_lens, uttrs, slot_p, tf_p,
                                        embedding, slot_emb, b_ih, b_hh,
                                        ws, h_all, out, preds_out);

    // 4) batched scores + softmax/scatter (tf==1 only)
    k_scores<<<512, 256, 0, stream>>>(h_all, enc_out, enc_lens, tf_p, scores_all);
    k_softmax_all<<<1024, 256, 0, stream>>>(scores_all, enc_lens, uttrs, tf_p,
                                            out, preds_out);
}

// Round 6
// 604.583 us; speedup vs baseline: 1.4413x; 1.4413x over previous
//
#include <hip/hip_runtime.h>
#include <math.h>

// Problem dims (fixed by reference)
#define Bsz 64
#define Ssz 512
#define Hsz 400
#define Dsz 400
#define Vsz 32000
#define Lsz 16
#define H3  1200   // 3*H

// Workspace layout (float offsets)
#define WT_HH_OFF 0                 // 400*1200 transposed W_hh [k][j]  (fallback only)
#define WT_IH_OFF 480000            // 400*1200 transposed W_ih [k][j]  (fallback only)
#define HQA_OFF   960000            // 25600  h ping  (float4 tiles [k4][b][4])
#define HQB_OFF   985600            // 25600  h pong
#define GI_OFF    1011200           // 16*1200*64   gi[t][j][b]
#define HALL_OFF  2240000           // 64*16*400    h_all[b][t][d]
#define SCALL_OFF 2649600           // 16*64*512    scores[t][b][s]
#define CTR_OFF   3173888           // barrier counter (uint) + pad
// total 3,173,952 floats = 12.7 MB

#define NCHAIN 80                   // d-sliced chain blocks (5 d each)

// ---------------------------------------------------------------------------
// k_init: zero 131 MB output + WT transposes (fallback) + h0 + barrier ctr.
// ---------------------------------------------------------------------------
__global__ __launch_bounds__(256) void k_init(const float* __restrict__ W_hh,
                                              const float* __restrict__ W_ih,
                                              const float* __restrict__ enc_hidden,
                                              float4* __restrict__ out4, int n4,
                                              float* __restrict__ ws) {
    const int R1 = n4 + 480000;
    const int R2 = R1 + 480000;
    const int R3 = R2 + 25600;
    const int R4 = R3 + 64;
    int stride = gridDim.x * 256;
    for (int i = blockIdx.x * 256 + threadIdx.x; i < R4; i += stride) {
        if (i < n4) {
            out4[i] = make_float4(0.f, 0.f, 0.f, 0.f);
        } else if (i < R1) {
            int r = i - n4;
            int k = r / 1200, j = r % 1200;
            ws[WT_HH_OFF + r] = W_hh[(size_t)j * Hsz + k];
        } else if (i < R2) {
            int r = i - R1;
            int k = r / 1200, j = r % 1200;
            ws[WT_IH_OFF + r] = W_ih[(size_t)j * Dsz + k];
        } else if (i < R3) {
            int r = i - R2;
            int k = r >> 6, b = r & 63;
            ws[HQA_OFF + (k >> 2) * 256 + b * 4 + (k & 3)] = enc_hidden[b * Hsz + k];
        } else {
            ((unsigned*)(ws + CTR_OFF))[i - R3] = 0u;
        }
    }
}

// ---------------------------------------------------------------------------
// k_gi (tf==1 only): gi[t][j][b] = (x_t[b] @ W_ih^T)[j], tiled GEMM.
// ---------------------------------------------------------------------------
__global__ __launch_bounds__(256) void k_gi(const int* __restrict__ tgt,
                                            const int* __restrict__ slot_p,
                                            const int* __restrict__ tf_p,
                                            const float* __restrict__ embedding,
                                            const float* __restrict__ slot_emb,
                                            const float* __restrict__ W_ih,
                                            float* __restrict__ gi) {
    if (tf_p[0] == 0) return;
    __shared__ float4 xs[100 * 64];   // 102.4 KB, [k4][b]

    int t  = blockIdx.x >> 4;
    int jc = blockIdx.x & 15;
    int tid = threadIdx.x;
    int lane = tid & 63, wv = tid >> 6;

    {
        int bb = tid & 63, q = tid >> 6;
        const float* src = (t == 0)
            ? (slot_emb + (size_t)slot_p[0] * Dsz)
            : (embedding + (size_t)tgt[bb * Lsz + (t - 1)] * Dsz);
        const float4* src4 = (const float4*)src;
        for (int k4 = q * 25; k4 < q * 25 + 25; ++k4) xs[k4 * 64 + bb] = src4[k4];
    }
    __syncthreads();

    for (int g = wv; g < 19; g += 4) {
        int j0l = g * 4;
        int nj = (j0l + 4 <= 75) ? 4 : (75 - j0l);
        int j0 = jc * 75 + j0l;
        const float4* w0 = (const float4*)(W_ih + (size_t)(j0 + 0) * Dsz);
        const float4* w1 = (const float4*)(W_ih + (size_t)(j0 + ((nj > 1) ? 1 : 0)) * Dsz);
        const float4* w2 = (const float4*)(W_ih + (size_t)(j0 + ((nj > 2) ? 2 : 0)) * Dsz);
        const float4* w3 = (const float4*)(W_ih + (size_t)(j0 + ((nj > 3) ? 3 : 0)) * Dsz);
        float a0 = 0.f, a1 = 0.f, a2 = 0.f, a3 = 0.f;
        for (int k4 = 0; k4 < 100; ++k4) {
            float4 xv = xs[k4 * 64 + lane];
            float4 r0 = w0[k4], r1 = w1[k4], r2 = w2[k4], r3 = w3[k4];
            a0 = fmaf(r0.x, xv.x, a0); a0 = fmaf(r0.y, xv.y, a0);
            a0 = fmaf(r0.z, xv.z, a0); a0 = fmaf(r0.w, xv.w, a0);
            a1 = fmaf(r1.x, xv.x, a1); a1 = fmaf(r1.y, xv.y, a1);
            a1 = fmaf(r1.z, xv.z, a1); a1 = fmaf(r1.w, xv.w, a1);
            a2 = fmaf(r2.x, xv.x, a2); a2 = fmaf(r2.y, xv.y, a2);
            a2 = fmaf(r2.z, xv.z, a2); a2 = fmaf(r2.w, xv.w, a2);
            a3 = fmaf(r3.x, xv.x, a3); a3 = fmaf(r3.y, xv.y, a3);
            a3 = fmaf(r3.z, xv.z, a3); a3 = fmaf(r3.w, xv.w, a3);
        }
        float* go = gi + ((size_t)t * H3 + j0) * 64 + lane;
        go[0] = a0;
        if (nj > 1) go[64] = a1;
        if (nj > 2) go[128] = a2;
        if (nj > 3) go[192] = a3;
    }
}

// ---------------------------------------------------------------------------
// k_chain: tf==1: 80 d-sliced blocks x 960 threads, W_hh slice resident in
// LDS. Barrier: IF-level atomics only (no threadfence, no acquire-spin).
// tf==0: blocks 0..63 run independent per-batch full decode.
// ---------------------------------------------------------------------------
struct SmemChain {
    float4 W4[15 * 100];    // 24.0 KB  W_hh slice rows
    float4 h4[100 * 64];    // 102.4 KB h staged [k4][b]
    float  part[2880];      // 11.5 KB  [ks][gate][dd][b]
};
struct SmemFallback {
    float part_i[3 * H3];
    float part_h[3 * H3];
    float hx[Hsz];
    float xv[Dsz];
    float sL[Ssz];
    float redv[15];
    int   redi[15];
    float bc_max, bc_sum;
    int   bc_idx;
};
union SmemU { SmemChain c; SmemFallback f; };

__device__ __forceinline__ float sigmoidf_(float x) { return 1.f / (1.f + expf(-x)); }

__global__ __launch_bounds__(960) void k_chain(const float* __restrict__ ws_ro,
                                               const float* __restrict__ gi,
                                               const float* __restrict__ W_hh,
                                               const float* __restrict__ enc_hidden,
                                               const float* __restrict__ enc_out,
                                               const int* __restrict__ lens,
                                               const int* __restrict__ uttrs,
                                               const int* __restrict__ slot_p,
                                               const int* __restrict__ tf_p,
                                               const float* __restrict__ embedding,
                                               const float* __restrict__ slot_emb,
                                               const float* __restrict__ b_ih,
                                               const float* __restrict__ b_hh,
                                               float* __restrict__ ws_rw,
                                               float* __restrict__ h_all,
                                               float* __restrict__ out_probs,
                                               float* __restrict__ preds_out) {
    __shared__ SmemU sm;
    const int tid = threadIdx.x;
    const int tf  = tf_p[0];

    if (tf != 0) {
        // ================= distributed h-chain =================
        const int b  = tid & 63;
        const int wv = tid >> 6;            // 0..14
        const int dd_w = wv % 5;
        const int ks   = wv / 5;            // 0..2
        const int D0 = blockIdx.x * 5;
        unsigned* ctr = (unsigned*)(ws_rw + CTR_OFF);

        // preload W_hh slice: 15 rows x 100 float4 (LDS-resident for all steps)
        for (int i = tid; i < 1500; i += 960) {
            int row = i / 100, k4 = i % 100;
            int g = row / 5, dd = row % 5;
            sm.c.W4[row * 100 + k4] =
                ((const float4*)(W_hh + (size_t)(g * Hsz + D0 + dd) * Hsz))[k4];
        }
        __syncthreads();

        const int k4beg = (ks == 0) ? 0 : (ks == 1) ? 34 : 68;
        const int k4end = (ks == 2) ? 100 : k4beg + 34;
        const float4* Wr = sm.c.W4 + (0 * 5 + dd_w) * 100;
        const float4* Wz = sm.c.W4 + (1 * 5 + dd_w) * 100;
        const float4* Wn = sm.c.W4 + (2 * 5 + dd_w) * 100;

        for (int t = 0; t < Lsz; ++t) {
            const float4* hq_cur = (const float4*)(ws_ro + ((t & 1) ? HQB_OFF : HQA_OFF));
            float*        hq_nxt = ws_rw + ((t & 1) ? HQA_OFF : HQB_OFF);

            // stage full h into LDS (post-inv lines refetch from IF: fresh)
            for (int i = tid; i < 6400; i += 960) sm.c.h4[i] = hq_cur[i];
            __syncthreads();

            // GEMV partials: wave wv handles (dd_w, k-split ks) for its lane's b
            float ar = 0.f, az = 0.f, an = 0.f;
            for (int k4 = k4beg; k4 < k4end; ++k4) {
                float4 hv = sm.c.h4[k4 * 64 + b];
                float4 wr = Wr[k4], wz = Wz[k4], wn = Wn[k4];
                ar = fmaf(wr.x, hv.x, ar); ar = fmaf(wr.y, hv.y, ar);
                ar = fmaf(wr.z, hv.z, ar); ar = fmaf(wr.w, hv.w, ar);
                az = fmaf(wz.x, hv.x, az); az = fmaf(wz.y, hv.y, az);
                az = fmaf(wz.z, hv.z, az); az = fmaf(wz.w, hv.w, az);
                an = fmaf(wn.x, hv.x, an); an = fmaf(wn.y, hv.y, an);
                an = fmaf(wn.z, hv.z, an); an = fmaf(wn.w, hv.w, an);
            }
            sm.c.part[((ks * 3 + 0) * 5 + dd_w) * 64 + b] = ar;
            sm.c.part[((ks * 3 + 1) * 5 + dd_w) * 64 + b] = az;
            sm.c.part[((ks * 3 + 2) * 5 + dd_w) * 64 + b] = an;
            __syncthreads();

            // finalize: WAVE 0 ONLY (so tid0's release-add covers all h stores)
            if (tid < 64) {
                int b2 = tid;
                #pragma unroll
                for (int dd = 0; dd < 5; ++dd) {
                    int d = D0 + dd;
                    float ghr = sm.c.part[((0 * 3 + 0) * 5 + dd) * 64 + b2]
                              + sm.c.part[((1 * 3 + 0) * 5 + dd) * 64 + b2]
                              + sm.c.part[((2 * 3 + 0) * 5 + dd) * 64 + b2] + b_hh[d];
                    float ghz = sm.c.part[((0 * 3 + 1) * 5 + dd) * 64 + b2]
                              + sm.c.part[((1 * 3 + 1) * 5 + dd) * 64 + b2]
                              + sm.c.part[((2 * 3 + 1) * 5 + dd) * 64 + b2] + b_hh[d + Hsz];
                    float ghn = sm.c.part[((0 * 3 + 2) * 5 + dd) * 64 + b2]
                              + sm.c.part[((1 * 3 + 2) * 5 + dd) * 64 + b2]
                              + sm.c.part[((2 * 3 + 2) * 5 + dd) * 64 + b2] + b_hh[d + 2 * Hsz];
                    float gir = gi[((size_t)t * H3 + d) * 64 + b2]            + b_ih[d];
                    float giz = gi[((size_t)t * H3 + d + Hsz) * 64 + b2]      + b_ih[d + Hsz];
                    float gin = gi[((size_t)t * H3 + d + 2 * Hsz) * 64 + b2]  + b_ih[d + 2 * Hsz];
                    float r = sigmoidf_(gir + ghr);
                    float z = sigmoidf_(giz + ghz);
                    float n = tanhf(gin + r * ghn);
                    float hp = ((const float*)sm.c.h4)[((d >> 2) * 64 + b2) * 4 + (d & 3)];
                    float hn = (1.f - z) * n + z * hp;
                    // device-visible (IF) store: remote XCDs read fresh after barrier
                    __hip_atomic_store(&hq_nxt[(d >> 2) * 256 + b2 * 4 + (d & 3)], hn,
                                       __ATOMIC_RELAXED, __HIP_MEMORY_SCOPE_AGENT);
                    // h_all consumed by later kernels: kernel-end flush suffices
                    h_all[(size_t)b2 * (Lsz * Hsz) + t * Hsz + d] = hn;
                }
            }

            if (t < Lsz - 1) {
                __syncthreads();
                if (tid == 0) {
                    // release fetch_add: drains wave0's h stores (vmcnt wait),
                    // then publishes arrival at IF
                    __hip_atomic_fetch_add(ctr, 1u, __ATOMIC_RELEASE,
                                           __HIP_MEMORY_SCOPE_AGENT);
                    unsigned target = (unsigned)NCHAIN * (t + 1);
                    // relaxed spin: NO per-poll cache invalidate
                    while (__hip_atomic_load(ctr, __ATOMIC_RELAXED,
                                             __HIP_MEMORY_SCOPE_AGENT) < target) {
                        __builtin_amdgcn_s_sleep(4);
                    }
                    // exactly one acquire (buffer_inv) per barrier
                    (void)__hip_atomic_load(ctr, __ATOMIC_ACQUIRE,
                                            __HIP_MEMORY_SCOPE_AGENT);
                }
                __syncthreads();
            }
        }
        return;
    }

    // ================= tf==0 fallback: per-batch independent decode =========
    if (blockIdx.x >= Bsz) return;
    const int b    = blockIdx.x;
    const int lane = tid & 63;
    const int w    = tid >> 6;          // 0..14
    const int jc   = tid % 300;
    const int ksf  = tid / 300;
    const int kbeg = ksf * 134;
    const int kend = (ksf == 2) ? Hsz : kbeg + 134;
    const int len  = lens[b];

    const float4* WTH4 = (const float4*)(ws_ro + WT_HH_OFF);
    const float4* WTI4 = (const float4*)(ws_ro + WT_IH_OFF);

    if (tid < Hsz) {
        sm.f.hx[tid] = enc_hidden[b * Hsz + tid];
        sm.f.xv[tid] = slot_emb[(size_t)slot_p[0] * Dsz + tid];
    }
    __syncthreads();

    for (int t = 0; t < Lsz; ++t) {
        if (tid < 900) {
            float4 ai = make_float4(0.f, 0.f, 0.f, 0.f);
            float4 ah = make_float4(0.f, 0.f, 0.f, 0.f);
            for (int k = kbeg; k < kend; ++k) {
                float4 wi = WTI4[(size_t)k * 300 + jc];
                float4 wh = WTH4[(size_t)k * 300 + jc];
                float x = sm.f.xv[k], h = sm.f.hx[k];
                ai.x = fmaf(wi.x, x, ai.x); ai.y = fmaf(wi.y, x, ai.y);
                ai.z = fmaf(wi.z, x, ai.z); ai.w = fmaf(wi.w, x, ai.w);
                ah.x = fmaf(wh.x, h, ah.x); ah.y = fmaf(wh.y, h, ah.y);
                ah.z = fmaf(wh.z, h, ah.z); ah.w = fmaf(wh.w, h, ah.w);
            }
            ((float4*)sm.f.part_i)[ksf * 300 + jc] = ai;
            ((float4*)sm.f.part_h)[ksf * 300 + jc] = ah;
        }
        __syncthreads();

        if (tid < Hsz) {
            int d = tid;
            float i_r = sm.f.part_i[d]           + sm.f.part_i[H3 + d]           + sm.f.part_i[2 * H3 + d]           + b_ih[d];
            float i_z = sm.f.part_i[d + Hsz]     + sm.f.part_i[H3 + d + Hsz]     + sm.f.part_i[2 * H3 + d + Hsz]     + b_ih[d + Hsz];
            float i_n = sm.f.part_i[d + 2 * Hsz] + sm.f.part_i[H3 + d + 2 * Hsz] + sm.f.part_i[2 * H3 + d + 2 * Hsz] + b_ih[d + 2 * Hsz];
            float h_r = sm.f.part_h[d]           + sm.f.part_h[H3 + d]           + sm.f.part_h[2 * H3 + d]           + b_hh[d];
            float h_z = sm.f.part_h[d + Hsz]     + sm.f.part_h[H3 + d + Hsz]     + sm.f.part_h[2 * H3 + d + Hsz]     + b_hh[d + Hsz];
            float h_n = sm.f.part_h[d + 2 * Hsz] + sm.f.part_h[H3 + d + 2 * Hsz] + sm.f.part_h[2 * H3 + d + 2 * Hsz] + b_hh[d + 2 * Hsz];
            float r = sigmoidf_(i_r + h_r);
            float z = sigmoidf_(i_z + h_z);
            float n = tanhf(i_n + r * h_n);
            sm.f.hx[d] = (1.f - z) * n + z * sm.f.hx[d];
        }
        __syncthreads();

        const float4* hx4 = (const float4*)sm.f.hx;
        for (int s = w; s < len; s += 15) {
            const float4* e4 = (const float4*)(enc_out + ((size_t)b * Ssz + s) * Hsz);
            float4 ev = e4[lane];
            float4 hv = hx4[lane];
            float acc = ev.x * hv.x + ev.y * hv.y + ev.z * hv.z + ev.w * hv.w;
            if (lane < 36) {
                float4 ev2 = e4[64 + lane];
                float4 hv2 = hx4[64 + lane];
                acc += ev2.x * hv2.x + ev2.y * hv2.y + ev2.z * hv2.z + ev2.w * hv2.w;
            }
            #pragma unroll
            for (int off = 32; off >= 1; off >>= 1) acc += __shfl_xor(acc, off, 64);
            if (lane == 0) sm.f.sL[s] = acc;
        }
        __syncthreads();

        float bv = -INFINITY; int bi = 0x7fffffff;
        for (int s = tid; s < len; s += 960) {
            float v = sm.f.sL[s];
            if (v > bv || (v == bv && s < bi)) { bv = v; bi = s; }
        }
        #pragma unroll
        for (int off = 32; off >= 1; off >>= 1) {
            float ov = __shfl_xor(bv, off, 64);
            int   oi = __shfl_xor(bi, off, 64);
            if (ov > bv || (ov == bv && oi < bi)) { bv = ov; bi = oi; }
        }
        if (lane == 0) { sm.f.redv[w] = bv; sm.f.redi[w] = bi; }
        __syncthreads();
        if (tid == 0) {
            float mv = sm.f.redv[0]; int mi = sm.f.redi[0];
            for (int i = 1; i < 15; ++i)
                if (sm.f.redv[i] > mv || (sm.f.redv[i] == mv && sm.f.redi[i] < mi)) {
                    mv = sm.f.redv[i]; mi = sm.f.redi[i];
                }
            sm.f.bc_max = mv; sm.f.bc_idx = mi;
        }
        __syncthreads();
        float maxv = sm.f.bc_max;
        int   amax = sm.f.bc_idx;

        float ls = 0.f;
        for (int s = tid; s < len; s += 960) {
            float e = expf(sm.f.sL[s] - maxv);
            sm.f.sL[s] = e;
            ls += e;
        }
        #pragma unroll
        for (int off = 32; off >= 1; off >>= 1) ls += __shfl_xor(ls, off, 64);
        if (lane == 0) sm.f.redv[w] = ls;
        __syncthreads();
        if (tid == 0) {
            float sms = 0.f;
            for (int i = 0; i < 15; ++i) sms += sm.f.redv[i];
            sm.f.bc_sum = sms;
        }
        __syncthreads();
        float sum = sm.f.bc_sum;

        float* orow = out_probs + (size_t)b * (Lsz * Vsz) + (size_t)t * Vsz;
        for (int s = tid; s < len; s += 960) {
            atomicAdd(&orow[uttrs[b * Ssz + s]], sm.f.sL[s] / sum);
        }

        int predtok = uttrs[b * Ssz + amax];
        if (tid == 0) preds_out[(size_t)t * Bsz + b] = (float)predtok;
        __syncthreads();
        if (tid < Dsz) sm.f.xv[tid] = embedding[(size_t)predtok * Dsz + tid];
        __syncthreads();
    }
}

// ---------------------------------------------------------------------------
// Batched scores (tf==1): scores[t][b][s] = h_t[b].enc_out[b][s], s < len[b].
// ---------------------------------------------------------------------------
__global__ __launch_bounds__(256) void k_scores(const float* __restrict__ h_all,
                                                const float* __restrict__ enc_out,
                                                const int* __restrict__ lens,
                                                const int* __restrict__ tf_p,
                                                float* __restrict__ scores_all) {
    if (tf_p[0] == 0) return;
    __shared__ float4 hS[Lsz * 100];   // 25.6 KB

    int b  = blockIdx.x >> 3;
    int sc = blockIdx.x & 7;
    int tid = threadIdx.x;
    int lane = tid & 63;
    int w = tid >> 6;

    const float4* h4g = (const float4*)(h_all + (size_t)b * (Lsz * Hsz));
    for (int i = tid; i < Lsz * 100; i += 256) hS[i] = h4g[i];
    __syncthreads();

    int len = lens[b];
    int l2 = 64 + ((lane < 36) ? lane : 0);
    float mult2 = (lane < 36) ? 1.f : 0.f;

    for (int i = 0; i < 16; ++i) {
        int s = sc * 64 + i * 4 + w;
        if (s >= len) continue;
        const float4* e4 = (const float4*)(enc_out + ((size_t)b * Ssz + s) * Hsz);
        float4 ev  = e4[lane];
        float4 ev2 = e4[l2];
        ev2.x *= mult2; ev2.y *= mult2; ev2.z *= mult2; ev2.w *= mult2;

        float acc[Lsz];
        #pragma unroll
        for (int t = 0; t < Lsz; ++t) {
            float4 hv  = hS[t * 100 + lane];
            float4 hv2 = hS[t * 100 + l2];
            float a = ev.x * hv.x + ev.y * hv.y + ev.z * hv.z + ev.w * hv.w;
            a += ev2.x * hv2.x + ev2.y * hv2.y + ev2.z * hv2.z + ev2.w * hv2.w;
            acc[t] = a;
        }
        #pragma unroll
        for (int off = 32; off >= 1; off >>= 1) {
            #pragma unroll
            for (int t = 0; t < Lsz; ++t) acc[t] += __shfl_xor(acc[t], off, 64);
        }
        if (lane == 0) {
            #pragma unroll
            for (int t = 0; t < Lsz; ++t)
                scores_all[(size_t)t * (Bsz * Ssz) + b * Ssz + s] = acc[t];
        }
    }
}

// ---------------------------------------------------------------------------
// Batched softmax + scatter + argmax (tf==1): 1024 blocks, one per (t,b).
// ---------------------------------------------------------------------------
__global__ __launch_bounds__(256) void k_softmax_all(const float* __restrict__ scores_all,
                                                     const int* __restrict__ lens,
                                                     const int* __restrict__ uttrs,
                                                     const int* __restrict__ tf_p,
                                                     float* __restrict__ out_probs,
                                                     float* __restrict__ preds_out) {
    if (tf_p[0] == 0) return;
    __shared__ float sL[Ssz];
    __shared__ float redv[4];
    __shared__ int   redi[4];
    __shared__ float bc_max, bc_sum;
    __shared__ int   bc_idx;

    int t = blockIdx.x >> 6;
    int b = blockIdx.x & 63;
    int tid = threadIdx.x;
    int lane = tid & 63, w = tid >> 6;
    int len = lens[b];
    const float* srow = scores_all + (size_t)t * (Bsz * Ssz) + b * Ssz;

    for (int s = tid; s < len; s += 256) sL[s] = srow[s];
    __syncthreads();

    float bv = -INFINITY; int bi = 0x7fffffff;
    for (int s = tid; s < len; s += 256) {
        float v = sL[s];
        if (v > bv || (v == bv && s < bi)) { bv = v; bi = s; }
    }
    #pragma unroll
    for (int off = 32; off >= 1; off >>= 1) {
        float ov = __shfl_xor(bv, off, 64);
        int   oi = __shfl_xor(bi, off, 64);
        if (ov > bv || (ov == bv && oi < bi)) { bv = ov; bi = oi; }
    }
    if (lane == 0) { redv[w] = bv; redi[w] = bi; }
    __syncthreads();
    if (tid == 0) {
        float mv = redv[0]; int mi = redi[0];
        for (int i = 1; i < 4; ++i)
            if (redv[i] > mv || (redv[i] == mv && redi[i] < mi)) { mv = redv[i]; mi = redi[i]; }
        bc_max = mv; bc_idx = mi;
    }
    __syncthreads();
    float maxv = bc_max;
    int   amax = bc_idx;

    float ls = 0.f;
    for (int s = tid; s < len; s += 256) {
        float e = expf(sL[s] - maxv);
        sL[s] = e;
        ls += e;
    }
    #pragma unroll
    for (int off = 32; off >= 1; off >>= 1) ls += __shfl_xor(ls, off, 64);
    if (lane == 0) redv[w] = ls;
    __syncthreads();
    if (tid == 0) bc_sum = redv[0] + redv[1] + redv[2] + redv[3];
    __syncthreads();
    float sum = bc_sum;

    float* orow = out_probs + (size_t)b * (Lsz * Vsz) + (size_t)t * Vsz;
    for (int s = tid; s < len; s += 256) {
        atomicAdd(&orow[uttrs[b * Ssz + s]], sL[s] / sum);
    }

    if (tid == 0) preds_out[(size_t)t * Bsz + b] = (float)uttrs[b * Ssz + amax];
}

// ---------------------------------------------------------------------------
extern "C" void kernel_launch(void* const* d_in, const int* in_sizes, int n_in,
                              void* d_out, int out_size, void* d_ws, size_t ws_size,
                              hipStream_t stream) {
    const float* enc_hidden = (const float*)d_in[0];
    const float* enc_out    = (const float*)d_in[1];
    const int*   enc_lens   = (const int*)d_in[2];
    const int*   uttrs      = (const int*)d_in[3];
    const int*   tgt        = (const int*)d_in[4];
    const int*   slot_p     = (const int*)d_in[5];
    const int*   tf_p       = (const int*)d_in[6];
    const float* embedding  = (const float*)d_in[7];
    const float* slot_emb   = (const float*)d_in[8];
    const float* W_ih       = (const float*)d_in[9];
    const float* W_hh       = (const float*)d_in[10];
    const float* b_ih       = (const float*)d_in[11];
    const float* b_hh       = (const float*)d_in[12];

    float* out = (float*)d_out;
    float* ws  = (float*)d_ws;

    float* gi_all     = ws + GI_OFF;
    float* h_all      = ws + HALL_OFF;
    float* scores_all = ws + SCALL_OFF;
    float* preds_out  = out + (size_t)Bsz * Lsz * Vsz;

    int n4 = out_size >> 2;

    // 1) init: zero output + WT transposes + h0 + barrier ctr
    k_init<<<2048, 256, 0, stream>>>(W_hh, W_ih, enc_hidden, (float4*)d_out, n4, ws);

    // 2) gi GEMM for all 16 steps (tf==1 only)
    k_gi<<<256, 256, 0, stream>>>(tgt, slot_p, tf_p, embedding, slot_emb,
                                  W_ih, gi_all);

    // 3) chain (tf==1: d-sliced distributed; tf==0: per-batch fallback)
    k_chain<<<NCHAIN, 960, 0, stream>>>(ws, gi_all, W_hh, enc_hidden, enc_out,
                                        enc_lens, uttrs, slot_p, tf_p,
                                        embedding, slot_emb, b_ih, b_hh,
                                        ws, h_all, out, preds_out);

    // 4) batched scores + softmax/scatter (tf==1 only)
    k_scores<<<512, 256, 0, stream>>>(h_all, enc_out, enc_lens, tf_p, scores_all);
    k_softmax_all<<<1024, 256, 0, stream>>>(scores_all, enc_lens, uttrs, tf_p,
                                            out, preds_out);
}